// Round 5
// baseline (227.401 us; speedup 1.0000x reference)
//
#include <hip/hip_runtime.h>
#include <math.h>
#include <stdint.h>

#define NA 32          // N_AGENTS
#define SD 2048        // STATE_DIM
#define BT 2048        // B = BS*T
#define NFRG 144       // col frags (2304 padded cols / 16); 128 agent + 12 tail + 4 pad

typedef float floatx4 __attribute__((ext_vector_type(4)));
typedef short bf16x8  __attribute__((ext_vector_type(8)));

__device__ __forceinline__ unsigned short f2bf(float f) {
    union { float f; uint32_t u; } v; v.f = f;
    uint32_t r = v.u + 0x7FFFu + ((v.u >> 16) & 1u);
    return (unsigned short)(r >> 16);
}

__device__ __forceinline__ void stage16(const void* g, void* l) {
    __builtin_amdgcn_global_load_lds(
        (const __attribute__((address_space(1))) void*)g,
        (__attribute__((address_space(3))) void*)l,
        16, 0, 0);
}

// ---- fragment layouts ----
// A-frag (stA):  elem((bt*64+kc)*512 + (quad*16+l16)*8 + j) = st[bt*16+l16][kc*32+quad*8+j]
// B-frag (Wswz): elem(((i*NFRG+f)*2+h)*512 + (quad*16+l16)*8 + j) = W[n=f*16+l16][k=i*64+h*32+quad*8+j]
// C-frag (Ycn, f32): elem((bt*NFRG+f)*256 + (quad*16+l16)*4 + r) = -Y[bt*16+quad*4+r][f*16+l16]

// ---------------- K0a: st -> A-fragment-order bf16 (coalesced writes) ----
__global__ __launch_bounds__(256) void k0_ast(const float* __restrict__ st,
                                              unsigned short* __restrict__ stA) {
    const int t  = threadIdx.x;
    const int kc = blockIdx.x * 4 + (t >> 6);   // 0..63
    const int bt = blockIdx.y;                  // 0..127
    const int l  = t & 63;
    const int quad = l >> 4, l16 = l & 15;
    const float* src = st + (size_t)(bt * 16 + l16) * SD + kc * 32 + quad * 8;
    float4 v0 = *(const float4*)(src);
    float4 v1 = *(const float4*)(src + 4);
    ushort4 o0, o1;
    o0.x = f2bf(v0.x); o0.y = f2bf(v0.y); o0.z = f2bf(v0.z); o0.w = f2bf(v0.w);
    o1.x = f2bf(v1.x); o1.y = f2bf(v1.y); o1.z = f2bf(v1.z); o1.w = f2bf(v1.w);
    unsigned short* dst = stA + ((size_t)bt * 64 + kc) * 512 + l * 8;
    *(ushort4*)(dst)     = o0;
    *(ushort4*)(dst + 4) = o1;
}

// ---------------- K0b: weights -> B-frag order (coalesced writes) --------
__global__ __launch_bounds__(256) void k0_wswz(const float* __restrict__ Ww1,
                                               const float* __restrict__ Wwf,
                                               const float* __restrict__ Wb1,
                                               const float* __restrict__ Wv1,
                                               unsigned short* __restrict__ Wswz) {
    const int t = threadIdx.x;
    const int i = blockIdx.y;                   // k-chunk 0..31
    const int f = blockIdx.x * 2 + (t >> 7);    // frag 0..143
    const int h = (t >> 6) & 1;
    const int l = t & 63;
    const int quad = l >> 4, l16 = l & 15;
    const int n = f * 16 + l16;

    const float* src; int ld, nr = 0;
    if (f < 128)      { src = Ww1; ld = 2048; nr = n; }
    else if (f < 132) { src = Wwf; ld = 64;   nr = n - 2048; }
    else if (f < 136) { src = Wb1; ld = 64;   nr = n - 2112; }
    else if (f < 140) { src = Wv1; ld = 64;   nr = n - 2176; }
    else              { src = nullptr; ld = 64; }

    const int k0 = i * 64 + h * 32 + quad * 8;
    unsigned short vals[8];
    #pragma unroll
    for (int j = 0; j < 8; j++)
        vals[j] = src ? f2bf(src[(size_t)(k0 + j) * ld + nr]) : (unsigned short)0;

    unsigned short* dst = Wswz + (((size_t)i * NFRG + f) * 2 + h) * 512 + l * 8;
    ushort4 o0 = {vals[0], vals[1], vals[2], vals[3]};
    ushort4 o1 = {vals[4], vals[5], vals[6], vals[7]};
    *(ushort4*)(dst)     = o0;
    *(ushort4*)(dst + 4) = o1;
}

// ---------------- K0c: concat bias (padded) ----------------
__global__ void k0_bias(const float* __restrict__ bw1, const float* __restrict__ bwf,
                        const float* __restrict__ bb1, const float* __restrict__ bv1,
                        float* __restrict__ bcat) {
    int n = blockIdx.x * 256 + threadIdx.x;
    if (n >= NFRG * 16) return;
    float v = 0.f;
    if (n < 2048)      v = bw1[n];
    else if (n < 2112) v = bwf[n - 2048];
    else if (n < 2176) v = bb1[n - 2112];
    else if (n < 2240) v = bv1[n - 2176];
    bcat[n] = v;
}

// ---------------- K1: Ycn = -(st @ Wcat + bias), fp32 fragment layout -----
// Register-streamed MFMA loop, software-pipelined one iteration.
__global__ __launch_bounds__(256) void k1_gemm(const unsigned short* __restrict__ stA,
                                               const unsigned short* __restrict__ Wswz,
                                               const float* __restrict__ bcat,
                                               float* __restrict__ Ycn)
{
    const int t = threadIdx.x;
    const int m0t = blockIdx.x * 4;   // btile base (64 rows)
    const int n0f = blockIdx.y * 8;   // frag base (128 cols)
    const int wid = t >> 6, lane = t & 63;
    const int wm = wid & 1, wn = wid >> 1;
    const int l16 = lane & 15;

    floatx4 acc[2][4];
    #pragma unroll
    for (int i = 0; i < 2; i++)
        #pragma unroll
        for (int j = 0; j < 4; j++) acc[i][j] = (floatx4)0.f;

    const unsigned short* Ap0 = stA + ((size_t)(m0t + wm * 2 + 0) * 64) * 512 + lane * 8;
    const unsigned short* Ap1 = stA + ((size_t)(m0t + wm * 2 + 1) * 64) * 512 + lane * 8;
    const unsigned short* Bbase = Wswz + ((size_t)(n0f + wn * 4) * 2) * 512 + lane * 8;

    bf16x8 a0c = *(const bf16x8*)(Ap0);
    bf16x8 a1c = *(const bf16x8*)(Ap1);
    bf16x8 bc[4];
    #pragma unroll
    for (int nf = 0; nf < 4; nf++)
        bc[nf] = *(const bf16x8*)(Bbase + (size_t)nf * 1024);

    for (int kc = 0; kc < 64; kc++) {
        bf16x8 a0n, a1n, bn[4];
        if (kc < 63) {
            const int kn = kc + 1;
            a0n = *(const bf16x8*)(Ap0 + (size_t)kn * 512);
            a1n = *(const bf16x8*)(Ap1 + (size_t)kn * 512);
            const unsigned short* Bp =
                Bbase + ((size_t)(kn >> 1) * NFRG * 2 + (kn & 1)) * 512;
            #pragma unroll
            for (int nf = 0; nf < 4; nf++)
                bn[nf] = *(const bf16x8*)(Bp + (size_t)nf * 1024);
        }
        #pragma unroll
        for (int nf = 0; nf < 4; nf++) {
            acc[0][nf] = __builtin_amdgcn_mfma_f32_16x16x32_bf16(a0c, bc[nf], acc[0][nf], 0, 0, 0);
            acc[1][nf] = __builtin_amdgcn_mfma_f32_16x16x32_bf16(a1c, bc[nf], acc[1][nf], 0, 0, 0);
        }
        a0c = a0n; a1c = a1n;
        #pragma unroll
        for (int nf = 0; nf < 4; nf++) bc[nf] = bn[nf];
    }

    #pragma unroll
    for (int mf = 0; mf < 2; mf++)
        #pragma unroll
        for (int nf = 0; nf < 4; nf++) {
            const int f  = n0f + wn * 4 + nf;
            const int bt = m0t + wm * 2 + mf;
            const float bias = bcat[f * 16 + l16];
            floatx4 o;
            #pragma unroll
            for (int r = 0; r < 4; r++) o[r] = -(acc[mf][nf][r] + bias);
            *(floatx4*)(Ycn + ((size_t)bt * NFRG + f) * 256 + lane * 4) = o;
        }
}

// ---------------- K3: q1[i][b] — mask-PAIR x 4-bt, depth-2 pipeline ------
// R4 resubmit (R3 bench was an infra failure, no data). Structure:
// TRIPLE-buffered W, prefetch depth 2 for BOTH W-stage and Ycn, ONE
// s_barrier/iter, counted vmcnt(8) that only waits on ops issued a full
// iteration earlier (~1000 cyc cover > L2/L3 latency).
// Per iter fg: compute(buf[fg%3], yv) -> issue stage(fg+2)+Ycn(fg+2)
// -> vmcnt(8) [waits stage(fg+1)+Ycn(fg+1), issued last iter] -> s_barrier.
// RAW: buf[fg] staged @fg-2, waited @fg-1, published by fg-1's barrier.
// WAR: stage(fg+2) overwrites buf[(fg-1)%3]; its readers' ds_reads
// completed (lgkmcnt before MFMA issue) before iter fg-1's barrier.
// SAFETY (new): vmcnt(0) drain after the loop — otherwise up to 8
// global_load_lds DMAs can still be in flight at s_endpgm and land in
// LDS after it is reassigned to a new workgroup (corruption).
// LDS 57.6 KB -> 2 blocks/CU. Groups: 0..31 agents, 32=wf, 33=b1, 34=v,
// 35=zero-pad (prefetched only).
__global__ __launch_bounds__(256) void k3_q1(
    const unsigned short* __restrict__ stA, const float* __restrict__ qs,
    const unsigned short* __restrict__ Wswz, const float* __restrict__ Wv2,
    const float* __restrict__ bv2, const float* __restrict__ Ycn,
    float* __restrict__ q1)
{
    const int p   = blockIdx.x;          // mask pair: masks p, p+16
    const int btg = blockIdx.y;          // bt group of 4
    const int t = threadIdx.x;
    const int w = t >> 6, lane = t & 63;
    const int bt = btg * 4 + w;
    const int quad = lane >> 4, l16 = lane & 15;
    const int im[2] = { p, p + 16 };

    __shared__ unsigned short Wl[3][2][4][2][512];  // [buf][mask][nf][half][512] = 48 KB
    __shared__ float qs_s[4][16][33];               // per-wave qs tile (same-wave RW only)

    // qs into LDS (written and read by the same wave -> no barrier needed)
    {
        int b = lane >> 2, a0 = (lane & 3) * 8;
        const float* src = qs + (size_t)(bt * 16 + b) * NA + a0;
        #pragma unroll
        for (int u = 0; u < 8; u++) qs_s[w][b][a0 + u] = src[u];
    }

    // A fragments (agent-i k-chunk of st) for both masks
    bf16x8 A0[2], A1[2];
    #pragma unroll
    for (int m = 0; m < 2; m++) {
        A0[m] = *(const bf16x8*)(stA + ((size_t)bt * 64 + 2 * im[m] + 0) * 512 + lane * 8);
        A1[m] = *(const bf16x8*)(stA + ((size_t)bt * 64 + 2 * im[m] + 1) * 512 + lane * 8);
    }

    const float* Yb = Ycn + (size_t)bt * NFRG * 256 + lane * 4;

    // stage group fg (4 frags, both masks) into buffer buf.
    // 16 chunks of 1 KB; this wave issues chunks c = w*4..w*4+3.
    auto stage = [&](int fg, int buf) {
        #pragma unroll
        for (int j = 0; j < 4; j++) {
            const int c  = w * 4 + j;          // 0..15
            const int m  = c >> 3;
            const int nf = (c >> 1) & 3;
            const int h  = c & 1;
            const unsigned short* gp = Wswz
                + ((size_t)(im[m] * NFRG + fg * 4 + nf) * 2 + h) * 512 + lane * 8;
            stage16(gp, &Wl[buf][m][nf][h][0]);
        }
    };

    floatx4 yv[4], yn1[4], yn2[4], acc[2][4];

    // MFMA chains for group in buffer buf; C-init = yv (shared by both masks)
    auto wmfma = [&](int buf) {
        #pragma unroll
        for (int m = 0; m < 2; m++)
            #pragma unroll
            for (int nf = 0; nf < 4; nf++) {
                bf16x8 w0 = *(const bf16x8*)&Wl[buf][m][nf][0][lane * 8];
                bf16x8 w1 = *(const bf16x8*)&Wl[buf][m][nf][1][lane * 8];
                floatx4 a = __builtin_amdgcn_mfma_f32_16x16x32_bf16(A0[m], w0, yv[nf], 0, 0, 0);
                acc[m][nf] = __builtin_amdgcn_mfma_f32_16x16x32_bf16(A1[m], w1, a, 0, 0, 0);
            }
    };

    floatx4 hid[2][4], wff[2][4], b1f[2][4], vacc[2];
    #pragma unroll
    for (int m = 0; m < 2; m++) {
        vacc[m] = (floatx4)0.f;
        #pragma unroll
        for (int nf = 0; nf < 4; nf++) hid[m][nf] = (floatx4)0.f;
    }

    // prologue: depth-2 prefetch (groups 0 and 1), then one stall (group 0)
    stage(0, 0);
    #pragma unroll
    for (int nf = 0; nf < 4; nf++) yv[nf]  = *(const floatx4*)(Yb + (size_t)nf * 256);
    stage(1, 1);
    #pragma unroll
    for (int nf = 0; nf < 4; nf++) yn1[nf] = *(const floatx4*)(Yb + (size_t)(4 + nf) * 256);
    __builtin_amdgcn_sched_barrier(0);
    asm volatile("s_waitcnt vmcnt(8)" ::: "memory");   // group-0 stage + yv complete
    __builtin_amdgcn_s_barrier();
    __builtin_amdgcn_sched_barrier(0);

    int bcur = 0;                                      // buffer index of group fg
    for (int fg = 0; fg < 35; fg++) {
        // ---- compute group fg ----
        wmfma(bcur);
        if (fg < 32) {
            float qv[4];
            #pragma unroll
            for (int r = 0; r < 4; r++) qv[r] = qs_s[w][quad * 4 + r][fg];
            #pragma unroll
            for (int m = 0; m < 2; m++)
                #pragma unroll
                for (int nf = 0; nf < 4; nf++)
                    #pragma unroll
                    for (int r = 0; r < 4; r++)
                        hid[m][nf][r] += qv[r] * fabsf(acc[m][nf][r]);
        } else if (fg == 32) {
            #pragma unroll
            for (int m = 0; m < 2; m++)
                #pragma unroll
                for (int nf = 0; nf < 4; nf++)
                    #pragma unroll
                    for (int r = 0; r < 4; r++) wff[m][nf][r] = fabsf(acc[m][nf][r]);
        } else if (fg == 33) {
            #pragma unroll
            for (int m = 0; m < 2; m++)
                #pragma unroll
                for (int nf = 0; nf < 4; nf++)
                    #pragma unroll
                    for (int r = 0; r < 4; r++) b1f[m][nf][r] = -acc[m][nf][r];
        } else {
            float wv2f[4];
            #pragma unroll
            for (int nf = 0; nf < 4; nf++) wv2f[nf] = Wv2[nf * 16 + l16];
            #pragma unroll
            for (int m = 0; m < 2; m++)
                #pragma unroll
                for (int nf = 0; nf < 4; nf++)
                    #pragma unroll
                    for (int r = 0; r < 4; r++)
                        vacc[m][r] += fmaxf(-acc[m][nf][r], 0.f) * wv2f[nf];
        }
        // ---- prefetch group fg+2 (W stage + Ycn), depth 2 ----
        if (fg <= 33) {
            int b2 = bcur + 2; if (b2 >= 3) b2 -= 3;
            stage(fg + 2, b2);
            const float* yp = Yb + (size_t)(fg + 2) * 4 * 256;
            #pragma unroll
            for (int nf = 0; nf < 4; nf++) yn2[nf] = *(const floatx4*)(yp + (size_t)nf * 256);
        }
        // ---- single stall-free wait + barrier ----
        __builtin_amdgcn_sched_barrier(0);
        asm volatile("s_waitcnt vmcnt(8)" ::: "memory"); // waits only on fg+1's prefetches (1 iter old)
        __builtin_amdgcn_s_barrier();                    // buf[fg+1] published to all waves
        __builtin_amdgcn_sched_barrier(0);
        // ---- rotate pipeline registers ----
        #pragma unroll
        for (int nf = 0; nf < 4; nf++) { yv[nf] = yn1[nf]; yn1[nf] = yn2[nf]; }
        bcur = (bcur == 2) ? 0 : bcur + 1;
    }

    // drain all in-flight DMA before epilogue/endpgm (LDS reassignment safety)
    asm volatile("s_waitcnt vmcnt(0)" ::: "memory");

    const float bv2v = bv2[0];
    #pragma unroll
    for (int m = 0; m < 2; m++)
        #pragma unroll
        for (int r = 0; r < 4; r++) {
            float s = vacc[m][r];
            #pragma unroll
            for (int nf = 0; nf < 4; nf++) {
                float h = hid[m][nf][r] + b1f[m][nf][r];
                h = h > 0.f ? h : expm1f(h);
                s += h * wff[m][nf][r];
            }
            s += __shfl_xor(s, 1); s += __shfl_xor(s, 2);
            s += __shfl_xor(s, 4); s += __shfl_xor(s, 8);
            if (l16 == 0) q1[(size_t)im[m] * BT + bt * 16 + quad * 4 + r] = s + bv2v;
        }
}

// ---------------- K4: q_tot, wc, final mix — fp32 fragment consumer ------
__global__ __launch_bounds__(256) void k4_final(
    const float* __restrict__ qs, const float* __restrict__ Ycn,
    const float* __restrict__ q1, const float* __restrict__ Wv2,
    const float* __restrict__ bv2, float* __restrict__ out)
{
    const int bt = blockIdx.x;
    __shared__ float qs_s[16][33];
    __shared__ float qw_s[16][33];
    __shared__ float hidp[4][16][64];
    __shared__ float wfb[16][64], b1b[16][64], vb[16][64];
    __shared__ float qt[16];

    const int t = threadIdx.x, w = t >> 6, lane = t & 63;
    const int quad = lane >> 4, l16 = lane & 15;
    const float bv2v = bv2[0];

    {
        int l = t * 2;
        float2 v = *(const float2*)&qs[(size_t)(bt * 16 + (l >> 5)) * NA + (l & 31)];
        qs_s[l >> 5][(l & 31) + 0] = v.x;
        qs_s[l >> 5][(l & 31) + 1] = v.y;
    }
    __syncthreads();

    const float* Yb = Ycn + (size_t)bt * NFRG * 256;

    // pass 1: hid with plain qs
    floatx4 hid[4];
    #pragma unroll
    for (int nf = 0; nf < 4; nf++) hid[nf] = (floatx4)0.f;
    for (int ia = 0; ia < 8; ia++) {
        const int a = w * 8 + ia;
        const float* yp = Yb + (size_t)(a * 4) * 256 + lane * 4;
        float qv[4];
        #pragma unroll
        for (int r = 0; r < 4; r++) qv[r] = qs_s[quad * 4 + r][a];
        #pragma unroll
        for (int nf = 0; nf < 4; nf++) {
            floatx4 c = *(const floatx4*)(yp + nf * 256);   // c = -Y
            #pragma unroll
            for (int r = 0; r < 4; r++) hid[nf][r] += qv[r] * fabsf(c[r]);
        }
    }
    #pragma unroll
    for (int nf = 0; nf < 4; nf++)
        #pragma unroll
        for (int r = 0; r < 4; r++)
            hidp[w][quad * 4 + r][nf * 16 + l16] = hid[nf][r];

    // tail frags: 3 per wave
    #pragma unroll
    for (int fi = 0; fi < 3; fi++) {
        const int nft = w * 3 + fi;
        floatx4 c = *(const floatx4*)(Yb + (size_t)(128 + nft) * 256 + lane * 4);
        const int e = (nft & 3) * 16 + l16;
        #pragma unroll
        for (int r = 0; r < 4; r++) {
            int b = quad * 4 + r;
            if (nft < 4)      wfb[b][e] = fabsf(c[r]);
            else if (nft < 8) b1b[b][e] = -c[r];
            else              vb[b][e]  = fmaxf(-c[r], 0.f) * Wv2[e];
        }
    }
    __syncthreads();

    // q_tot for rows w*4..w*4+3
    #pragma unroll
    for (int bb = 0; bb < 4; bb++) {
        int b = w * 4 + bb;
        float h = hidp[0][b][lane] + hidp[1][b][lane]
                + hidp[2][b][lane] + hidp[3][b][lane] + b1b[b][lane];
        h = h > 0.f ? h : expm1f(h);
        float val = h * wfb[b][lane] + vb[b][lane];
        #pragma unroll
        for (int off = 32; off > 0; off >>= 1) val += __shfl_xor(val, off);
        if (lane == 0) qt[b] = val + bv2v;
    }
    __syncthreads();

    // wc: thread (w,quad,l16) -> row rr = w*4+quad, agents 2*l16, 2*l16+1
    {
        const int rr = w * 4 + quad;
        float qtv = qt[rr];
        float d0 = fabsf(qtv - q1[(size_t)(2 * l16 + 0) * BT + bt * 16 + rr]);
        float d1 = fabsf(qtv - q1[(size_t)(2 * l16 + 1) * BT + bt * 16 + rr]);
        float ss = d0 * d0 + d1 * d1;
        ss += __shfl_xor(ss, 1); ss += __shfl_xor(ss, 2);
        ss += __shfl_xor(ss, 4); ss += __shfl_xor(ss, 8);
        float inv = 1.f / fmaxf(sqrtf(ss), 1e-12f);
        qw_s[rr][2 * l16 + 0] = qs_s[rr][2 * l16 + 0] * d0 * inv;
        qw_s[rr][2 * l16 + 1] = qs_s[rr][2 * l16 + 1] * d1 * inv;
    }
    __syncthreads();

    // pass 2: hid with qs*wc
    floatx4 hid2[4];
    #pragma unroll
    for (int nf = 0; nf < 4; nf++) hid2[nf] = (floatx4)0.f;
    for (int ia = 0; ia < 8; ia++) {
        const int a = w * 8 + ia;
        const float* yp = Yb + (size_t)(a * 4) * 256 + lane * 4;
        float qv[4];
        #pragma unroll
        for (int r = 0; r < 4; r++) qv[r] = qw_s[quad * 4 + r][a];
        #pragma unroll
        for (int nf = 0; nf < 4; nf++) {
            floatx4 c = *(const floatx4*)(yp + nf * 256);
            #pragma unroll
            for (int r = 0; r < 4; r++) hid2[nf][r] += qv[r] * fabsf(c[r]);
        }
    }
    #pragma unroll
    for (int nf = 0; nf < 4; nf++)
        #pragma unroll
        for (int r = 0; r < 4; r++)
            hidp[w][quad * 4 + r][nf * 16 + l16] = hid2[nf][r];
    __syncthreads();

    #pragma unroll
    for (int bb = 0; bb < 4; bb++) {
        int b = w * 4 + bb;
        float h = hidp[0][b][lane] + hidp[1][b][lane]
                + hidp[2][b][lane] + hidp[3][b][lane] + b1b[b][lane];
        h = h > 0.f ? h : expm1f(h);
        float val = h * wfb[b][lane] + vb[b][lane];
        #pragma unroll
        for (int off = 32; off > 0; off >>= 1) val += __shfl_xor(val, off);
        if (lane == 0) out[bt * 16 + b] = val + bv2v;
    }
}

extern "C" void kernel_launch(void* const* d_in, const int* in_sizes, int n_in,
                              void* d_out, int out_size, void* d_ws, size_t ws_size,
                              hipStream_t stream) {
    const float* qs  = (const float*)d_in[0];
    const float* st  = (const float*)d_in[1];
    const float* Ww1 = (const float*)d_in[2];
    const float* bw1 = (const float*)d_in[3];
    const float* Wwf = (const float*)d_in[4];
    const float* bwf = (const float*)d_in[5];
    const float* Wb1 = (const float*)d_in[6];
    const float* bb1 = (const float*)d_in[7];
    const float* Wv1 = (const float*)d_in[8];
    const float* bv1 = (const float*)d_in[9];
    const float* Wv2 = (const float*)d_in[10];
    const float* bv2 = (const float*)d_in[11];
    float* out = (float*)d_out;

    // workspace (~37 MB, same footprint as proven R3-R7 layout)
    float* Ycn           = (float*)d_ws;                           // 128*144*256 f32 = 18.87 MB
    unsigned short* stA  = (unsigned short*)(Ycn + (size_t)128 * NFRG * 256); // 8.39 MB
    unsigned short* Wswz = stA + (size_t)SD * SD;                  // 32*144*1024 bf16 = 9.44 MB
    float* bcat          = (float*)(Wswz + (size_t)32 * NFRG * 1024); // 2304 f32
    float* q1v           = bcat + NFRG * 16;                       // 32*2048 f32

    k0_ast <<<dim3(16, 128), 256, 0, stream>>>(st, stA);
    k0_wswz<<<dim3(NFRG / 2, 32), 256, 0, stream>>>(Ww1, Wwf, Wb1, Wv1, Wswz);
    k0_bias<<<(NFRG * 16 + 255) / 256, 256, 0, stream>>>(bw1, bwf, bb1, bv1, bcat);

    k1_gemm<<<dim3(BT / 64, NFRG / 8), 256, 0, stream>>>(stA, Wswz, bcat, Ycn);
    k3_q1  <<<dim3(16, 32), 256, 0, stream>>>(stA, qs, Wswz, Wv2, bv2, Ycn, q1v);
    k4_final<<<BT / 16, 256, 0, stream>>>(qs, Ycn, q1v, Wv2, bv2, out);
}

// Round 6
// 182.666 us; speedup vs baseline: 1.2449x; 1.2449x over previous
//
#include <hip/hip_runtime.h>
#include <math.h>
#include <stdint.h>

#define NA 32          // N_AGENTS
#define SD 2048        // STATE_DIM
#define BT 2048        // B = BS*T
#define NFRG 144       // col frags (2304 padded cols / 16); 128 agent + 12 tail + 4 pad

typedef float floatx4 __attribute__((ext_vector_type(4)));
typedef short bf16x8  __attribute__((ext_vector_type(8)));

__device__ __forceinline__ unsigned short f2bf(float f) {
    union { float f; uint32_t u; } v; v.f = f;
    uint32_t r = v.u + 0x7FFFu + ((v.u >> 16) & 1u);
    return (unsigned short)(r >> 16);
}

__device__ __forceinline__ void stage16(const void* g, void* l) {
    __builtin_amdgcn_global_load_lds(
        (const __attribute__((address_space(1))) void*)g,
        (__attribute__((address_space(3))) void*)l,
        16, 0, 0);
}

// ---- fragment layouts ----
// A-frag (stA):  elem((bt*64+kc)*512 + (quad*16+l16)*8 + j) = st[bt*16+l16][kc*32+quad*8+j]
// B-frag (Wswz): elem(((i*NFRG+f)*2+h)*512 + (quad*16+l16)*8 + j) = W[n=f*16+l16][k=i*64+h*32+quad*8+j]
// C-frag (Ycn, f32): elem((bt*NFRG+f)*256 + (quad*16+l16)*4 + r) = -Y[bt*16+quad*4+r][f*16+l16]

// ---------------- K0a: st -> A-fragment-order bf16 (coalesced writes) ----
__global__ __launch_bounds__(256) void k0_ast(const float* __restrict__ st,
                                              unsigned short* __restrict__ stA) {
    const int t  = threadIdx.x;
    const int kc = blockIdx.x * 4 + (t >> 6);   // 0..63
    const int bt = blockIdx.y;                  // 0..127
    const int l  = t & 63;
    const int quad = l >> 4, l16 = l & 15;
    const float* src = st + (size_t)(bt * 16 + l16) * SD + kc * 32 + quad * 8;
    float4 v0 = *(const float4*)(src);
    float4 v1 = *(const float4*)(src + 4);
    ushort4 o0, o1;
    o0.x = f2bf(v0.x); o0.y = f2bf(v0.y); o0.z = f2bf(v0.z); o0.w = f2bf(v0.w);
    o1.x = f2bf(v1.x); o1.y = f2bf(v1.y); o1.z = f2bf(v1.z); o1.w = f2bf(v1.w);
    unsigned short* dst = stA + ((size_t)bt * 64 + kc) * 512 + l * 8;
    *(ushort4*)(dst)     = o0;
    *(ushort4*)(dst + 4) = o1;
}

// ---------------- K0b: weights -> B-frag order (coalesced writes) --------
__global__ __launch_bounds__(256) void k0_wswz(const float* __restrict__ Ww1,
                                               const float* __restrict__ Wwf,
                                               const float* __restrict__ Wb1,
                                               const float* __restrict__ Wv1,
                                               unsigned short* __restrict__ Wswz) {
    const int t = threadIdx.x;
    const int i = blockIdx.y;                   // k-chunk 0..31
    const int f = blockIdx.x * 2 + (t >> 7);    // frag 0..143
    const int h = (t >> 6) & 1;
    const int l = t & 63;
    const int quad = l >> 4, l16 = l & 15;
    const int n = f * 16 + l16;

    const float* src; int ld, nr = 0;
    if (f < 128)      { src = Ww1; ld = 2048; nr = n; }
    else if (f < 132) { src = Wwf; ld = 64;   nr = n - 2048; }
    else if (f < 136) { src = Wb1; ld = 64;   nr = n - 2112; }
    else if (f < 140) { src = Wv1; ld = 64;   nr = n - 2176; }
    else              { src = nullptr; ld = 64; }

    const int k0 = i * 64 + h * 32 + quad * 8;
    unsigned short vals[8];
    #pragma unroll
    for (int j = 0; j < 8; j++)
        vals[j] = src ? f2bf(src[(size_t)(k0 + j) * ld + nr]) : (unsigned short)0;

    unsigned short* dst = Wswz + (((size_t)i * NFRG + f) * 2 + h) * 512 + l * 8;
    ushort4 o0 = {vals[0], vals[1], vals[2], vals[3]};
    ushort4 o1 = {vals[4], vals[5], vals[6], vals[7]};
    *(ushort4*)(dst)     = o0;
    *(ushort4*)(dst + 4) = o1;
}

// ---------------- K1: Ycn = -(st @ Wcat + bias), LDS-staged tiles --------
// R5: replace register-streamed loads (x2 intra-block redundancy, ~864 MB
// L2 traffic) with the k3-R1-proven staging pattern: global_load_lds
// double buffer, stage(next) -> compute(cur) -> one __syncthreads per
// iter. Tile 64x128 (4 btiles x 8 frags), K-step = 2 kc -> 32 iters,
// LDS 48 KB -> 2-3 blocks/CU. Traffic halves to ~432 MB; loads get a
// full compute phase of cover. Bias computed inline (k0_bias removed).
__global__ __launch_bounds__(256) void k1_gemm(const unsigned short* __restrict__ stA,
                                               const unsigned short* __restrict__ Wswz,
                                               const float* __restrict__ bw1,
                                               const float* __restrict__ bwf,
                                               const float* __restrict__ bb1,
                                               const float* __restrict__ bv1,
                                               float* __restrict__ Ycn)
{
    const int t = threadIdx.x;
    const int m0t = blockIdx.x * 4;   // btile base (64 rows)
    const int n0f = blockIdx.y * 8;   // frag base (128 cols)
    const int wid = t >> 6, lane = t & 63;
    const int wm = wid & 1, wn = wid >> 1;
    const int l16 = lane & 15;

    __shared__ unsigned short As[2][2][4][512];   // [buf][kk][btile][512] = 16 KB
    __shared__ unsigned short Bs[2][2][8][512];   // [buf][kk][frag ][512] = 32 KB

    floatx4 acc[2][4];
    #pragma unroll
    for (int i = 0; i < 2; i++)
        #pragma unroll
        for (int j = 0; j < 4; j++) acc[i][j] = (floatx4)0.f;

    // stage iteration 'it' (kc = it*2, it*2+1) into buffer buf.
    // 24 chunks of 1 KB; this wave issues chunks c = wid*6 .. wid*6+5.
    // LDS dest is wave-uniform base + lane*16 (lane-linear = frag layout).
    auto stage = [&](int it, int buf) {
        #pragma unroll
        for (int j = 0; j < 6; j++) {
            const int c   = wid * 6 + j;        // 0..23
            const int kk  = c / 12;             // 0..1
            const int rem = c % 12;
            if (rem < 4) {
                const unsigned short* gp = stA
                    + ((size_t)(m0t + rem) * 64 + (it * 2 + kk)) * 512 + lane * 8;
                stage16(gp, &As[buf][kk][rem][0]);
            } else {
                const int f = rem - 4;          // 0..7
                const unsigned short* gp = Wswz
                    + (((size_t)it * NFRG + (n0f + f)) * 2 + kk) * 512 + lane * 8;
                stage16(gp, &Bs[buf][kk][f][0]);
            }
        }
    };

    stage(0, 0);
    __syncthreads();

    for (int it = 0; it < 32; it++) {
        const int buf = it & 1;
        if (it < 31) stage(it + 1, buf ^ 1);
        #pragma unroll
        for (int kk = 0; kk < 2; kk++) {
            bf16x8 a0 = *(const bf16x8*)&As[buf][kk][wm * 2 + 0][lane * 8];
            bf16x8 a1 = *(const bf16x8*)&As[buf][kk][wm * 2 + 1][lane * 8];
            bf16x8 b[4];
            #pragma unroll
            for (int nf = 0; nf < 4; nf++)
                b[nf] = *(const bf16x8*)&Bs[buf][kk][wn * 4 + nf][lane * 8];
            #pragma unroll
            for (int nf = 0; nf < 4; nf++) {
                acc[0][nf] = __builtin_amdgcn_mfma_f32_16x16x32_bf16(a0, b[nf], acc[0][nf], 0, 0, 0);
                acc[1][nf] = __builtin_amdgcn_mfma_f32_16x16x32_bf16(a1, b[nf], acc[1][nf], 0, 0, 0);
            }
        }
        __syncthreads();
    }

    #pragma unroll
    for (int mf = 0; mf < 2; mf++)
        #pragma unroll
        for (int nf = 0; nf < 4; nf++) {
            const int f  = n0f + wn * 4 + nf;
            const int bt = m0t + wm * 2 + mf;
            const int n  = f * 16 + l16;
            float bias;
            if (f < 128)      bias = bw1[n];
            else if (f < 132) bias = bwf[n - 2048];
            else if (f < 136) bias = bb1[n - 2112];
            else if (f < 140) bias = bv1[n - 2176];
            else              bias = 0.f;
            floatx4 o;
            #pragma unroll
            for (int r = 0; r < 4; r++) o[r] = -(acc[mf][nf][r] + bias);
            *(floatx4*)(Ycn + ((size_t)bt * NFRG + f) * 256 + lane * 4) = o;
        }
}

// ---------------- K3: q1[i][b] — mask-PAIR x 4-bt blocks, LDS-staged W ---
// Reverted verbatim to the proven R1 version (46.2 us, passed): 4 waves
// share one mask pair (p, p+16); wave w owns bt = btg*4+w; W staged per
// frag-group into LDS (double-buffered, global_load_lds width=16); each
// wave computes BOTH masks with the Ycn fragment as shared MFMA C-init.
// R2-R4 lesson: every hand-pipelined variant (GPB=2, raw s_barrier +
// counted vmcnt, depth-2 triple-buffer) LOST to this simple
// stage -> compute -> __syncthreads loop. Do not re-pipeline this kernel.
__global__ __launch_bounds__(256) void k3_q1(
    const unsigned short* __restrict__ stA, const float* __restrict__ qs,
    const unsigned short* __restrict__ Wswz, const float* __restrict__ Wv2,
    const float* __restrict__ bv2, const float* __restrict__ Ycn,
    float* __restrict__ q1)
{
    const int p   = blockIdx.x;          // mask pair: masks p, p+16
    const int btg = blockIdx.y;          // bt group of 4
    const int t = threadIdx.x;
    const int w = t >> 6, lane = t & 63;
    const int bt = btg * 4 + w;
    const int quad = lane >> 4, l16 = lane & 15;
    const int im[2] = { p, p + 16 };

    __shared__ unsigned short Wl[2][2][4][2][512];  // [buf][mask][nf][half][512] = 32 KB
    __shared__ float qs_s[4][16][33];               // per-wave qs tile

    // qs into LDS (per wave)
    {
        int b = lane >> 2, a0 = (lane & 3) * 8;
        const float* src = qs + (size_t)(bt * 16 + b) * NA + a0;
        #pragma unroll
        for (int u = 0; u < 8; u++) qs_s[w][b][a0 + u] = src[u];
    }

    // A fragments (agent-i k-chunk of st) for both masks
    bf16x8 A0[2], A1[2];
    #pragma unroll
    for (int m = 0; m < 2; m++) {
        A0[m] = *(const bf16x8*)(stA + ((size_t)bt * 64 + 2 * im[m] + 0) * 512 + lane * 8);
        A1[m] = *(const bf16x8*)(stA + ((size_t)bt * 64 + 2 * im[m] + 1) * 512 + lane * 8);
    }

    const float* Yb = Ycn + (size_t)bt * NFRG * 256 + lane * 4;

    // stage frag-group fg (frags fg*4..fg*4+3, both masks) into buffer buf.
    // 16 chunks of 1 KB; this wave issues chunks c = w*4..w*4+3.
    auto stage = [&](int fg, int buf) {
        #pragma unroll
        for (int j = 0; j < 4; j++) {
            const int c  = w * 4 + j;          // 0..15
            const int m  = c >> 3;
            const int nf = (c >> 1) & 3;
            const int h  = c & 1;
            const unsigned short* g = Wswz
                + ((size_t)(im[m] * NFRG + fg * 4 + nf) * 2 + h) * 512 + lane * 8;
            stage16(g, &Wl[buf][m][nf][h][0]);
        }
    };

    floatx4 yv[4], yn[4], acc[2][4];

    // ds_read both masks' W for current group and run both MFMA chains,
    // sharing yv as C-init.
    auto wmfma = [&](int buf) {
        #pragma unroll
        for (int m = 0; m < 2; m++)
            #pragma unroll
            for (int nf = 0; nf < 4; nf++) {
                bf16x8 w0 = *(const bf16x8*)&Wl[buf][m][nf][0][lane * 8];
                bf16x8 w1 = *(const bf16x8*)&Wl[buf][m][nf][1][lane * 8];
                floatx4 a = __builtin_amdgcn_mfma_f32_16x16x32_bf16(A0[m], w0, yv[nf], 0, 0, 0);
                acc[m][nf] = __builtin_amdgcn_mfma_f32_16x16x32_bf16(A1[m], w1, a, 0, 0, 0);
            }
    };

    floatx4 hid[2][4];
    #pragma unroll
    for (int m = 0; m < 2; m++)
        #pragma unroll
        for (int nf = 0; nf < 4; nf++) hid[m][nf] = (floatx4)0.f;

    // prologue: stage group 0, prefetch Ycn group 0
    stage(0, 0);
    #pragma unroll
    for (int nf = 0; nf < 4; nf++) yv[nf] = *(const floatx4*)(Yb + (size_t)nf * 256);
    __syncthreads();

    // main agent loop: groups 0..31 (agents)
    for (int fg = 0; fg < 32; fg++) {
        const int cur = fg & 1;
        stage(fg + 1, cur ^ 1);
        {
            const float* yp = Yb + (size_t)(fg + 1) * 4 * 256;
            #pragma unroll
            for (int nf = 0; nf < 4; nf++) yn[nf] = *(const floatx4*)(yp + (size_t)nf * 256);
        }
        wmfma(cur);
        float qv[4];
        #pragma unroll
        for (int r = 0; r < 4; r++) qv[r] = qs_s[w][quad * 4 + r][fg];
        #pragma unroll
        for (int m = 0; m < 2; m++)
            #pragma unroll
            for (int nf = 0; nf < 4; nf++)
                #pragma unroll
                for (int r = 0; r < 4; r++)
                    hid[m][nf][r] += qv[r] * fabsf(acc[m][nf][r]);
        #pragma unroll
        for (int nf = 0; nf < 4; nf++) yv[nf] = yn[nf];
        __syncthreads();
    }

    floatx4 wff[2][4], b1f[2][4], vacc[2];

    // group 32: wf frags (128..131)   [uses buf 0; fg=31 staged into buf 0]
    {
        stage(33, 1);
        {
            const float* yp = Yb + (size_t)33 * 4 * 256;
            #pragma unroll
            for (int nf = 0; nf < 4; nf++) yn[nf] = *(const floatx4*)(yp + (size_t)nf * 256);
        }
        wmfma(0);
        #pragma unroll
        for (int m = 0; m < 2; m++)
            #pragma unroll
            for (int nf = 0; nf < 4; nf++)
                #pragma unroll
                for (int r = 0; r < 4; r++) wff[m][nf][r] = fabsf(acc[m][nf][r]);
        #pragma unroll
        for (int nf = 0; nf < 4; nf++) yv[nf] = yn[nf];
        __syncthreads();
    }
    // group 33: b1 frags (132..135)
    {
        stage(34, 0);
        {
            const float* yp = Yb + (size_t)34 * 4 * 256;
            #pragma unroll
            for (int nf = 0; nf < 4; nf++) yn[nf] = *(const floatx4*)(yp + (size_t)nf * 256);
        }
        wmfma(1);
        #pragma unroll
        for (int m = 0; m < 2; m++)
            #pragma unroll
            for (int nf = 0; nf < 4; nf++)
                #pragma unroll
                for (int r = 0; r < 4; r++) b1f[m][nf][r] = -acc[m][nf][r];
        #pragma unroll
        for (int nf = 0; nf < 4; nf++) yv[nf] = yn[nf];
        __syncthreads();
    }
    // group 34: v frags (136..139)
    {
        wmfma(0);
        float wv2f[4];
        #pragma unroll
        for (int nf = 0; nf < 4; nf++) wv2f[nf] = Wv2[nf * 16 + l16];
        #pragma unroll
        for (int m = 0; m < 2; m++) {
            vacc[m] = (floatx4)0.f;
            #pragma unroll
            for (int nf = 0; nf < 4; nf++)
                #pragma unroll
                for (int r = 0; r < 4; r++)
                    vacc[m][r] += fmaxf(-acc[m][nf][r], 0.f) * wv2f[nf];
        }
    }

    const float bv2v = bv2[0];
    #pragma unroll
    for (int m = 0; m < 2; m++)
        #pragma unroll
        for (int r = 0; r < 4; r++) {
            float s = vacc[m][r];
            #pragma unroll
            for (int nf = 0; nf < 4; nf++) {
                float h = hid[m][nf][r] + b1f[m][nf][r];
                h = h > 0.f ? h : expm1f(h);
                s += h * wff[m][nf][r];
            }
            s += __shfl_xor(s, 1); s += __shfl_xor(s, 2);
            s += __shfl_xor(s, 4); s += __shfl_xor(s, 8);
            if (l16 == 0) q1[(size_t)im[m] * BT + bt * 16 + quad * 4 + r] = s + bv2v;
        }
}

// ---------------- K4: q_tot, wc, final mix — fp32 fragment consumer ------
__global__ __launch_bounds__(256) void k4_final(
    const float* __restrict__ qs, const float* __restrict__ Ycn,
    const float* __restrict__ q1, const float* __restrict__ Wv2,
    const float* __restrict__ bv2, float* __restrict__ out)
{
    const int bt = blockIdx.x;
    __shared__ float qs_s[16][33];
    __shared__ float qw_s[16][33];
    __shared__ float hidp[4][16][64];
    __shared__ float wfb[16][64], b1b[16][64], vb[16][64];
    __shared__ float qt[16];

    const int t = threadIdx.x, w = t >> 6, lane = t & 63;
    const int quad = lane >> 4, l16 = lane & 15;
    const float bv2v = bv2[0];

    {
        int l = t * 2;
        float2 v = *(const float2*)&qs[(size_t)(bt * 16 + (l >> 5)) * NA + (l & 31)];
        qs_s[l >> 5][(l & 31) + 0] = v.x;
        qs_s[l >> 5][(l & 31) + 1] = v.y;
    }
    __syncthreads();

    const float* Yb = Ycn + (size_t)bt * NFRG * 256;

    // pass 1: hid with plain qs
    floatx4 hid[4];
    #pragma unroll
    for (int nf = 0; nf < 4; nf++) hid[nf] = (floatx4)0.f;
    for (int ia = 0; ia < 8; ia++) {
        const int a = w * 8 + ia;
        const float* yp = Yb + (size_t)(a * 4) * 256 + lane * 4;
        float qv[4];
        #pragma unroll
        for (int r = 0; r < 4; r++) qv[r] = qs_s[quad * 4 + r][a];
        #pragma unroll
        for (int nf = 0; nf < 4; nf++) {
            floatx4 c = *(const floatx4*)(yp + nf * 256);   // c = -Y
            #pragma unroll
            for (int r = 0; r < 4; r++) hid[nf][r] += qv[r] * fabsf(c[r]);
        }
    }
    #pragma unroll
    for (int nf = 0; nf < 4; nf++)
        #pragma unroll
        for (int r = 0; r < 4; r++)
            hidp[w][quad * 4 + r][nf * 16 + l16] = hid[nf][r];

    // tail frags: 3 per wave
    #pragma unroll
    for (int fi = 0; fi < 3; fi++) {
        const int nft = w * 3 + fi;
        floatx4 c = *(const floatx4*)(Yb + (size_t)(128 + nft) * 256 + lane * 4);
        const int e = (nft & 3) * 16 + l16;
        #pragma unroll
        for (int r = 0; r < 4; r++) {
            int b = quad * 4 + r;
            if (nft < 4)      wfb[b][e] = fabsf(c[r]);
            else if (nft < 8) b1b[b][e] = -c[r];
            else              vb[b][e]  = fmaxf(-c[r], 0.f) * Wv2[e];
        }
    }
    __syncthreads();

    // q_tot for rows w*4..w*4+3
    #pragma unroll
    for (int bb = 0; bb < 4; bb++) {
        int b = w * 4 + bb;
        float h = hidp[0][b][lane] + hidp[1][b][lane]
                + hidp[2][b][lane] + hidp[3][b][lane] + b1b[b][lane];
        h = h > 0.f ? h : expm1f(h);
        float val = h * wfb[b][lane] + vb[b][lane];
        #pragma unroll
        for (int off = 32; off > 0; off >>= 1) val += __shfl_xor(val, off);
        if (lane == 0) qt[b] = val + bv2v;
    }
    __syncthreads();

    // wc: thread (w,quad,l16) -> row rr = w*4+quad, agents 2*l16, 2*l16+1
    {
        const int rr = w * 4 + quad;
        float qtv = qt[rr];
        float d0 = fabsf(qtv - q1[(size_t)(2 * l16 + 0) * BT + bt * 16 + rr]);
        float d1 = fabsf(qtv - q1[(size_t)(2 * l16 + 1) * BT + bt * 16 + rr]);
        float ss = d0 * d0 + d1 * d1;
        ss += __shfl_xor(ss, 1); ss += __shfl_xor(ss, 2);
        ss += __shfl_xor(ss, 4); ss += __shfl_xor(ss, 8);
        float inv = 1.f / fmaxf(sqrtf(ss), 1e-12f);
        qw_s[rr][2 * l16 + 0] = qs_s[rr][2 * l16 + 0] * d0 * inv;
        qw_s[rr][2 * l16 + 1] = qs_s[rr][2 * l16 + 1] * d1 * inv;
    }
    __syncthreads();

    // pass 2: hid with qs*wc
    floatx4 hid2[4];
    #pragma unroll
    for (int nf = 0; nf < 4; nf++) hid2[nf] = (floatx4)0.f;
    for (int ia = 0; ia < 8; ia++) {
        const int a = w * 8 + ia;
        const float* yp = Yb + (size_t)(a * 4) * 256 + lane * 4;
        float qv[4];
        #pragma unroll
        for (int r = 0; r < 4; r++) qv[r] = qw_s[quad * 4 + r][a];
        #pragma unroll
        for (int nf = 0; nf < 4; nf++) {
            floatx4 c = *(const floatx4*)(yp + nf * 256);
            #pragma unroll
            for (int r = 0; r < 4; r++) hid2[nf][r] += qv[r] * fabsf(c[r]);
        }
    }
    #pragma unroll
    for (int nf = 0; nf < 4; nf++)
        #pragma unroll
        for (int r = 0; r < 4; r++)
            hidp[w][quad * 4 + r][nf * 16 + l16] = hid2[nf][r];
    __syncthreads();

    #pragma unroll
    for (int bb = 0; bb < 4; bb++) {
        int b = w * 4 + bb;
        float h = hidp[0][b][lane] + hidp[1][b][lane]
                + hidp[2][b][lane] + hidp[3][b][lane] + b1b[b][lane];
        h = h > 0.f ? h : expm1f(h);
        float val = h * wfb[b][lane] + vb[b][lane];
        #pragma unroll
        for (int off = 32; off > 0; off >>= 1) val += __shfl_xor(val, off);
        if (lane == 0) out[bt * 16 + b] = val + bv2v;
    }
}

extern "C" void kernel_launch(void* const* d_in, const int* in_sizes, int n_in,
                              void* d_out, int out_size, void* d_ws, size_t ws_size,
                              hipStream_t stream) {
    const float* qs  = (const float*)d_in[0];
    const float* st  = (const float*)d_in[1];
    const float* Ww1 = (const float*)d_in[2];
    const float* bw1 = (const float*)d_in[3];
    const float* Wwf = (const float*)d_in[4];
    const float* bwf = (const float*)d_in[5];
    const float* Wb1 = (const float*)d_in[6];
    const float* bb1 = (const float*)d_in[7];
    const float* Wv1 = (const float*)d_in[8];
    const float* bv1 = (const float*)d_in[9];
    const float* Wv2 = (const float*)d_in[10];
    const float* bv2 = (const float*)d_in[11];
    float* out = (float*)d_out;

    // workspace (~37 MB, same footprint as proven layout; bcat slot unused)
    float* Ycn           = (float*)d_ws;                           // 128*144*256 f32 = 18.87 MB
    unsigned short* stA  = (unsigned short*)(Ycn + (size_t)128 * NFRG * 256); // 8.39 MB
    unsigned short* Wswz = stA + (size_t)SD * SD;                  // 32*144*1024 bf16 = 9.44 MB
    float* bcat          = (float*)(Wswz + (size_t)32 * NFRG * 1024); // 2304 f32 (unused)
    float* q1v           = bcat + NFRG * 16;                       // 32*2048 f32

    k0_ast <<<dim3(16, 128), 256, 0, stream>>>(st, stA);
    k0_wswz<<<dim3(NFRG / 2, 32), 256, 0, stream>>>(Ww1, Wwf, Wb1, Wv1, Wswz);

    k1_gemm<<<dim3(BT / 64, NFRG / 8), 256, 0, stream>>>(stA, Wswz, bw1, bwf, bb1, bv1, Ycn);
    k3_q1  <<<dim3(16, 32), 256, 0, stream>>>(stA, qs, Wswz, Wv2, bv2, Ycn, q1v);
    k4_final<<<BT / 16, 256, 0, stream>>>(qs, Ycn, q1v, Wv2, bv2, out);
}